// Round 3
// baseline (29451.010 us; speedup 1.0000x reference)
//
#include <hip/hip_runtime.h>
#include <cmath>

// Problem constants: B=16, T=512, S=320, H=512, K=1024, NQ=4, M=B*T=8192

// ---------------- generic 64x64 tile f32 GEMM ----------------
// BT=true : C[m][n] = sum_k A[m][k] * B[n][k]   (B is N x K row-major)
// BT=false: C[m][n] = sum_k A[m][k] * B[k][n]   (B is K x N row-major)
template<bool BT>
__global__ __launch_bounds__(256)
void gemm64(const float* __restrict__ A, const float* __restrict__ B,
            float* __restrict__ C, int M, int N, int K,
            const float* __restrict__ bias1, const float* __restrict__ bias2)
{
    __shared__ float Al[32][68];
    __shared__ float Bl[32][68];
    const int m0 = blockIdx.y * 64, n0 = blockIdx.x * 64;
    const int t = threadIdx.x;
    const int tm = t >> 4, tn = t & 15;
    float acc[4][4] = {{0.f, 0.f, 0.f, 0.f}};

    for (int k0 = 0; k0 < K; k0 += 32) {
        #pragma unroll
        for (int i = 0; i < 2; i++) {
            int f4 = t + i * 256;
            int row = f4 >> 3, c4 = f4 & 7;
            float4 v = *(const float4*)(A + (size_t)(m0 + row) * K + k0 + c4 * 4);
            Al[c4*4+0][row] = v.x; Al[c4*4+1][row] = v.y;
            Al[c4*4+2][row] = v.z; Al[c4*4+3][row] = v.w;
        }
        if (BT) {
            #pragma unroll
            for (int i = 0; i < 2; i++) {
                int f4 = t + i * 256;
                int row = f4 >> 3, c4 = f4 & 7;
                float4 v = *(const float4*)(B + (size_t)(n0 + row) * K + k0 + c4 * 4);
                Bl[c4*4+0][row] = v.x; Bl[c4*4+1][row] = v.y;
                Bl[c4*4+2][row] = v.z; Bl[c4*4+3][row] = v.w;
            }
        } else {
            #pragma unroll
            for (int i = 0; i < 2; i++) {
                int f4 = t + i * 256;
                int kk = f4 >> 4, c4 = f4 & 15;
                float4 v = *(const float4*)(B + (size_t)(k0 + kk) * N + n0 + c4 * 4);
                *(float4*)&Bl[kk][c4 * 4] = v;
            }
        }
        __syncthreads();
        #pragma unroll
        for (int k = 0; k < 32; k++) {
            float4 a4 = *(const float4*)&Al[k][tm * 4];
            float4 b4 = *(const float4*)&Bl[k][tn * 4];
            float av[4] = {a4.x, a4.y, a4.z, a4.w};
            float bv[4] = {b4.x, b4.y, b4.z, b4.w};
            #pragma unroll
            for (int i = 0; i < 4; i++)
                #pragma unroll
                for (int j = 0; j < 4; j++)
                    acc[i][j] = fmaf(av[i], bv[j], acc[i][j]);
        }
        __syncthreads();
    }
    float bn[4];
    #pragma unroll
    for (int j = 0; j < 4; j++) {
        float bb = 0.f;
        if (bias1) bb += bias1[n0 + tn * 4 + j];
        if (bias2) bb += bias2[n0 + tn * 4 + j];
        bn[j] = bb;
    }
    #pragma unroll
    for (int i = 0; i < 4; i++) {
        float4 o;
        o.x = acc[i][0] + bn[0]; o.y = acc[i][1] + bn[1];
        o.z = acc[i][2] + bn[2]; o.w = acc[i][3] + bn[3];
        *(float4*)(C + (size_t)(m0 + tm * 4 + i) * N + n0 + tn * 4) = o;
    }
}

// ---------------- LayerNorm + ReLU in place ----------------
__global__ __launch_bounds__(256)
void ln_relu_kernel(float* __restrict__ X, const float* __restrict__ g,
                    const float* __restrict__ bb)
{
    __shared__ float red[256];
    __shared__ float stat[2];
    const int row = blockIdx.x, t = threadIdx.x;
    float x0 = X[(size_t)row * 512 + t];
    float x1 = X[(size_t)row * 512 + 256 + t];
    red[t] = x0 + x1;
    __syncthreads();
    for (int o = 128; o > 0; o >>= 1) { if (t < o) red[t] += red[t + o]; __syncthreads(); }
    if (t == 0) stat[0] = red[0] * (1.f / 512.f);
    __syncthreads();
    float mu = stat[0];
    float d0 = x0 - mu, d1 = x1 - mu;
    red[t] = d0 * d0 + d1 * d1;
    __syncthreads();
    for (int o = 128; o > 0; o >>= 1) { if (t < o) red[t] += red[t + o]; __syncthreads(); }
    if (t == 0) stat[1] = red[0] * (1.f / 512.f);
    __syncthreads();
    float rs = rsqrtf(stat[1] + 1e-5f);
    float y0 = d0 * rs * g[t] + bb[t];
    float y1 = d1 * rs * g[256 + t] + bb[256 + t];
    X[(size_t)row * 512 + t] = fmaxf(y0, 0.f);
    X[(size_t)row * 512 + 256 + t] = fmaxf(y1, 0.f);
}

// ---------------- codebook row squared-norms ----------------
__global__ __launch_bounds__(256)
void rownorm_kernel(const float* __restrict__ Ein, float* __restrict__ norms)
{
    __shared__ float red[256];
    const int row = blockIdx.x, t = threadIdx.x;
    float a = Ein[(size_t)row * 512 + t];
    float b = Ein[(size_t)row * 512 + 256 + t];
    red[t] = a * a + b * b;
    __syncthreads();
    for (int o = 128; o > 0; o >>= 1) { if (t < o) red[t] += red[t + o]; __syncthreads(); }
    if (t == 0) norms[row] = red[0];
}

// ---------------- VQ argmin + STE update ----------------
__global__ __launch_bounds__(256)
void vq_update_kernel(const float* __restrict__ D, const float* __restrict__ norms,
                      const float* __restrict__ cb, float* __restrict__ residual,
                      float* __restrict__ quant, float* __restrict__ loss_acc,
                      int first)
{
    __shared__ unsigned long long red[256];
    __shared__ float fred[256];
    __shared__ int sidx;
    __shared__ float sdmin;
    const int tok = blockIdx.x, t = threadIdx.x;
    unsigned long long best = ~0ull;
    #pragma unroll
    for (int i = 0; i < 4; i++) {
        int k = t + i * 256;
        float d = fmaf(-2.f, D[(size_t)tok * 1024 + k], norms[k]);
        unsigned u = __float_as_uint(d);
        u = (u & 0x80000000u) ? ~u : (u | 0x80000000u);
        unsigned long long p = ((unsigned long long)u << 32) | (unsigned)k;
        best = p < best ? p : best;
    }
    red[t] = best;
    __syncthreads();
    for (int o = 128; o > 0; o >>= 1) {
        if (t < o) red[t] = red[t + o] < red[t] ? red[t + o] : red[t];
        __syncthreads();
    }
    if (t == 0) {
        unsigned long long r0 = red[0];
        sidx = (int)(r0 & 0xffffffffu);
        unsigned uv = (unsigned)(r0 >> 32);
        unsigned orig = (uv & 0x80000000u) ? (uv ^ 0x80000000u) : ~uv;
        sdmin = __uint_as_float(orig);
    }
    float r0v = residual[(size_t)tok * 512 + t];
    float r1v = residual[(size_t)tok * 512 + 256 + t];
    fred[t] = r0v * r0v + r1v * r1v;
    __syncthreads();
    for (int o = 128; o > 0; o >>= 1) { if (t < o) fred[t] += fred[t + o]; __syncthreads(); }
    int idx = sidx;
    if (t == 0) atomicAdd(loss_acc, sdmin + fred[0]);
    const float* E = cb + (size_t)idx * 512;
    float e0 = E[t], e1 = E[256 + t];
    float q0 = r0v + (e0 - r0v);
    float q1 = r1v + (e1 - r1v);
    residual[(size_t)tok * 512 + t]       = r0v - q0;
    residual[(size_t)tok * 512 + 256 + t] = r1v - q1;
    if (first) {
        quant[(size_t)tok * 512 + t]       = q0;
        quant[(size_t)tok * 512 + 256 + t] = q1;
    } else {
        quant[(size_t)tok * 512 + t]       += q0;
        quant[(size_t)tok * 512 + 256 + t] += q1;
    }
}

// ---------------- fused 2-layer LSTM, custom fast grid barrier ----------------
#define GRPSZ 32
#define NGRP 8

__device__ __forceinline__ void arrive_wait(unsigned* bar, int g, unsigned tgt)
{
    // monotonic hierarchical barrier; caller fenced (release) before entry.
    // bounded spin: on timeout, proceed — arrivals are cumulative, so all
    // generations still complete (wrong answer instead of a hang).
    unsigned r = __hip_atomic_fetch_add(bar + g * 32, 1u, __ATOMIC_RELAXED,
                                        __HIP_MEMORY_SCOPE_AGENT);
    if (r == tgt * GRPSZ - 1) {
        unsigned rr = __hip_atomic_fetch_add(bar + 256, 1u, __ATOMIC_RELAXED,
                                             __HIP_MEMORY_SCOPE_AGENT);
        if (rr == tgt * NGRP - 1)
            __hip_atomic_store(bar + 288, tgt, __ATOMIC_RELAXED,
                               __HIP_MEMORY_SCOPE_AGENT);
    }
    int spins = 0;
    while (__hip_atomic_load(bar + 288, __ATOMIC_RELAXED,
                             __HIP_MEMORY_SCOPE_AGENT) < tgt) {
        __builtin_amdgcn_s_sleep(2);
        if (++spins > 20000) break;
    }
}

__device__ __forceinline__ float dot32(const float* hb, const float (&w)[32])
{
    float a0 = 0.f, a1 = 0.f, a2 = 0.f, a3 = 0.f;
    #pragma unroll
    for (int k4 = 0; k4 < 8; k4++) {
        float4 h4 = ((const float4*)hb)[k4];
        a0 = fmaf(h4.x, w[k4 * 4 + 0], a0);
        a1 = fmaf(h4.y, w[k4 * 4 + 1], a1);
        a2 = fmaf(h4.z, w[k4 * 4 + 2], a2);
        a3 = fmaf(h4.w, w[k4 * 4 + 3], a3);
    }
    return (a0 + a1) + (a2 + a3);
}

// blocks 0..127: layer 1 (hidden unit slice j = bid*4..+3)
// blocks 128..255: layer 2, running at step lag 1 (consumes h1[s-1])
// Plain launch: 256 blocks x 256 thr, ~50KB LDS -> >=1 block/CU co-resident.
__global__ __launch_bounds__(256)
void lstm_fused_kernel(const float* __restrict__ P1,
                       const float* __restrict__ wh1,
                       const float* __restrict__ wi2,
                       const float* __restrict__ wh2,
                       const float* __restrict__ bi2,
                       const float* __restrict__ bh2,
                       float* __restrict__ H2out,
                       float* __restrict__ h1A, float* __restrict__ h1B,
                       float* __restrict__ h2A, float* __restrict__ h2B,
                       unsigned* __restrict__ bar)
{
    __shared__ float hl[16 * 512];     // 32 KB staging
    __shared__ float part[16 * 256];   // 16 KB partials
    __shared__ float gl[256];
    __shared__ float c_lds[64];

    const int t = threadIdx.x;
    const int role = blockIdx.x >> 7;      // 0: layer1, 1: layer2
    const int bid = blockIdx.x & 127;
    const int cl = t & 15, ks = t >> 4;    // dot-phase mapping
    const int gate = cl >> 2, jj = cl & 3;
    const int j_base = bid * 4;
    const int cl_r = t >> 4, b_r = t & 15; // reduction-phase mapping
    const int gate_r = cl_r >> 2, jj_r = cl_r & 3;
    const int g = blockIdx.x >> 5;         // barrier group (8 x 32)

    float wrh[32], wrx[32];
    {
        const float* whp = (role == 0) ? wh1 : wh2;
        const float* wrow = whp + (size_t)(gate * 512 + j_base + jj) * 512 + ks * 32;
        #pragma unroll
        for (int i = 0; i < 32; i++) wrh[i] = wrow[i];
    }
    if (role == 1) {
        const float* wrow = wi2 + (size_t)(gate * 512 + j_base + jj) * 512 + ks * 32;
        #pragma unroll
        for (int i = 0; i < 32; i++) wrx[i] = wrow[i];
    } else {
        #pragma unroll
        for (int i = 0; i < 32; i++) wrx[i] = 0.f;
    }
    float bias2v = 0.f;
    if (role == 1) {
        int col = gate_r * 512 + j_base + jj_r;
        bias2v = bi2[col] + bh2[col];
    }
    if (t < 64) {
        c_lds[t] = 0.f;
        int b = t >> 2;
        float* h0 = (role == 0) ? h1A : h2A;
        h0[b * 512 + j_base + (t & 3)] = 0.f;
    }
    __threadfence();
    __syncthreads();
    if (t == 0) arrive_wait(bar, g, 1);
    __syncthreads();
    __threadfence();

    for (int s = 0; s < 513; s++) {
        if (role == 0) {
            if (s < 512) {
                const int step = s;
                const float* hin = (step & 1) ? h1B : h1A;
                float* hout = (step & 1) ? h1A : h1B;
                for (int i = t; i < 2048; i += 256)
                    ((float4*)hl)[i] = ((const float4*)hin)[i];
                float pv = P1[(size_t)(b_r * 512 + step) * 2048 + gate_r * 512 + j_base + jj_r];
                __syncthreads();
                float accb[16];
                #pragma unroll
                for (int b = 0; b < 16; b++)
                    accb[b] = dot32(hl + b * 512 + ks * 32, wrh);
                #pragma unroll
                for (int b = 0; b < 16; b++)
                    part[ks * 256 + cl * 16 + b] = accb[b];
                __syncthreads();
                float gv = pv;
                #pragma unroll
                for (int k = 0; k < 16; k++)
                    gv += part[k * 256 + cl_r * 16 + b_r];
                gl[cl_r * 16 + b_r] = gv;
                __syncthreads();
                if (t < 64) {
                    int b = t >> 2, jr = t & 3;
                    float iv = gl[(0 + jr) * 16 + b];
                    float fv = gl[(4 + jr) * 16 + b];
                    float gg = gl[(8 + jr) * 16 + b];
                    float ov = gl[(12 + jr) * 16 + b];
                    float ig = 1.f / (1.f + expf(-iv));
                    float fg = 1.f / (1.f + expf(-fv));
                    float og = 1.f / (1.f + expf(-ov));
                    float cn = fg * c_lds[t] + ig * tanhf(gg);
                    float hn = og * tanhf(cn);
                    c_lds[t] = cn;
                    hout[b * 512 + j_base + jr] = hn;
                }
            }
        } else {
            if (s >= 1) {
                const int m = s - 1;
                const float* xin = (m & 1) ? h1A : h1B;   // h1[m]
                const float* hin = (m & 1) ? h2B : h2A;   // h2[m-1]
                float* hout = (m & 1) ? h2A : h2B;        // h2[m]
                for (int i = t; i < 2048; i += 256)
                    ((float4*)hl)[i] = ((const float4*)xin)[i];
                __syncthreads();
                float accb[16];
                #pragma unroll
                for (int b = 0; b < 16; b++)
                    accb[b] = dot32(hl + b * 512 + ks * 32, wrx);
                __syncthreads();   // done reading x slice
                for (int i = t; i < 2048; i += 256)
                    ((float4*)hl)[i] = ((const float4*)hin)[i];
                __syncthreads();
                #pragma unroll
                for (int b = 0; b < 16; b++)
                    accb[b] += dot32(hl + b * 512 + ks * 32, wrh);
                #pragma unroll
                for (int b = 0; b < 16; b++)
                    part[ks * 256 + cl * 16 + b] = accb[b];
                __syncthreads();
                float gv = bias2v;
                #pragma unroll
                for (int k = 0; k < 16; k++)
                    gv += part[k * 256 + cl_r * 16 + b_r];
                gl[cl_r * 16 + b_r] = gv;
                __syncthreads();
                if (t < 64) {
                    int b = t >> 2, jr = t & 3;
                    float iv = gl[(0 + jr) * 16 + b];
                    float fv = gl[(4 + jr) * 16 + b];
                    float gg = gl[(8 + jr) * 16 + b];
                    float ov = gl[(12 + jr) * 16 + b];
                    float ig = 1.f / (1.f + expf(-iv));
                    float fg = 1.f / (1.f + expf(-fv));
                    float og = 1.f / (1.f + expf(-ov));
                    float cn = fg * c_lds[t] + ig * tanhf(gg);
                    float hn = og * tanhf(cn);
                    c_lds[t] = cn;
                    int j = j_base + jr;
                    hout[b * 512 + j] = hn;
                    H2out[(size_t)(b * 512 + m) * 512 + j] = hn;
                }
            }
        }
        if (s < 512) {
            __threadfence();           // release this block's h stores
            __syncthreads();
            if (t == 0) arrive_wait(bar, g, (unsigned)(s + 2));
            __syncthreads();
            __threadfence();           // acquire: invalidate L1 before reading peers' h
        }
    }
}

__global__ void finalize_loss_kernel(const float* __restrict__ acc, float* __restrict__ out)
{
    int q = threadIdx.x;
    if (q < 4) out[2621440 + q] = acc[q] * (1.f / 4194304.f);
}

extern "C" void kernel_launch(void* const* d_in, const int* in_sizes, int n_in,
                              void* d_out, int out_size, void* d_ws, size_t ws_size,
                              hipStream_t stream)
{
    const float* waveform  = (const float*)d_in[0];
    const float* enc_w     = (const float*)d_in[1];
    const float* enc_b     = (const float*)d_in[2];
    const float* ln_g      = (const float*)d_in[3];
    const float* ln_b      = (const float*)d_in[4];
    const float* codebooks = (const float*)d_in[5];
    const float* lstm_wi   = (const float*)d_in[6];
    const float* lstm_wh   = (const float*)d_in[7];
    const float* lstm_bi   = (const float*)d_in[8];
    const float* lstm_bh   = (const float*)d_in[9];
    const float* dec_w     = (const float*)d_in[10];
    const float* dec_b     = (const float*)d_in[11];
    float* out = (float*)d_out;

    float* ws = (float*)d_ws;                  // float offsets
    float* residual = ws;                      // 4,194,304
    float* quant    = ws + 4194304;            // 4,194,304
    float* H2       = ws + 8388608;            // 4,194,304
    float* big      = ws + 12582912;           // 16,777,216 (VQ D, then LSTM P1)
    float* h1A      = ws + 29360128;           // 8192
    float* h1B      = ws + 29368320;           // 8192
    float* h2A      = ws + 29376512;           // 8192
    float* h2B      = ws + 29384704;           // 8192
    float* norms    = ws + 29392896;           // 4096
    float* loss_acc = ws + 29396992;           // 16
    unsigned* bar   = (unsigned*)(ws + 29397504); // 512 u32

    hipMemsetAsync(loss_acc, 0, 16 * sizeof(float), stream);
    hipMemsetAsync(bar, 0, 512 * sizeof(unsigned), stream);

    // Encoder
    gemm64<false><<<dim3(8, 128), 256, 0, stream>>>(waveform, enc_w, residual,
                                                    8192, 512, 320, enc_b, nullptr);
    ln_relu_kernel<<<8192, 256, 0, stream>>>(residual, ln_g, ln_b);

    // Residual VQ
    rownorm_kernel<<<4096, 256, 0, stream>>>(codebooks, norms);
    for (int q = 0; q < 4; q++) {
        const float* cb = codebooks + (size_t)q * 1024 * 512;
        gemm64<true><<<dim3(16, 128), 256, 0, stream>>>(residual, cb, big,
                                                        8192, 1024, 512, nullptr, nullptr);
        vq_update_kernel<<<8192, 256, 0, stream>>>(big, norms + q * 1024, cb,
                                                   residual, quant, loss_acc + q, q == 0);
    }

    // P1 = quant @ wi1^T + bi1 + bh1
    gemm64<true><<<dim3(32, 128), 256, 0, stream>>>(quant, lstm_wi, big,
                                                    8192, 2048, 512, lstm_bi, lstm_bh);
    // Fused 2-layer LSTM (layer2 pipelined at lag 1) — PLAIN launch, custom barrier
    lstm_fused_kernel<<<dim3(256), dim3(256), 0, stream>>>(
        big, lstm_wh, lstm_wi + (size_t)2048 * 512, lstm_wh + (size_t)2048 * 512,
        lstm_bi + 2048, lstm_bh + 2048, H2, h1A, h1B, h2A, h2B, bar);

    // Decoder -> d_out
    gemm64<false><<<dim3(5, 128), 256, 0, stream>>>(H2, dec_w, out,
                                                    8192, 320, 512, dec_b, nullptr);
    finalize_loss_kernel<<<1, 4, 0, stream>>>(loss_acc, out);
}

// Round 4
// 5909.931 us; speedup vs baseline: 4.9833x; 4.9833x over previous
//
#include <hip/hip_runtime.h>
#include <cmath>

// Problem constants: B=16, T=512, S=320, H=512, K=1024, NQ=4, M=B*T=8192

// ---------------- generic 64x64 tile f32 GEMM ----------------
template<bool BT>
__global__ __launch_bounds__(256)
void gemm64(const float* __restrict__ A, const float* __restrict__ B,
            float* __restrict__ C, int M, int N, int K,
            const float* __restrict__ bias1, const float* __restrict__ bias2)
{
    __shared__ float Al[32][68];
    __shared__ float Bl[32][68];
    const int m0 = blockIdx.y * 64, n0 = blockIdx.x * 64;
    const int t = threadIdx.x;
    const int tm = t >> 4, tn = t & 15;
    float acc[4][4] = {{0.f, 0.f, 0.f, 0.f}};

    for (int k0 = 0; k0 < K; k0 += 32) {
        #pragma unroll
        for (int i = 0; i < 2; i++) {
            int f4 = t + i * 256;
            int row = f4 >> 3, c4 = f4 & 7;
            float4 v = *(const float4*)(A + (size_t)(m0 + row) * K + k0 + c4 * 4);
            Al[c4*4+0][row] = v.x; Al[c4*4+1][row] = v.y;
            Al[c4*4+2][row] = v.z; Al[c4*4+3][row] = v.w;
        }
        if (BT) {
            #pragma unroll
            for (int i = 0; i < 2; i++) {
                int f4 = t + i * 256;
                int row = f4 >> 3, c4 = f4 & 7;
                float4 v = *(const float4*)(B + (size_t)(n0 + row) * K + k0 + c4 * 4);
                Bl[c4*4+0][row] = v.x; Bl[c4*4+1][row] = v.y;
                Bl[c4*4+2][row] = v.z; Bl[c4*4+3][row] = v.w;
            }
        } else {
            #pragma unroll
            for (int i = 0; i < 2; i++) {
                int f4 = t + i * 256;
                int kk = f4 >> 4, c4 = f4 & 15;
                float4 v = *(const float4*)(B + (size_t)(k0 + kk) * N + n0 + c4 * 4);
                *(float4*)&Bl[kk][c4 * 4] = v;
            }
        }
        __syncthreads();
        #pragma unroll
        for (int k = 0; k < 32; k++) {
            float4 a4 = *(const float4*)&Al[k][tm * 4];
            float4 b4 = *(const float4*)&Bl[k][tn * 4];
            float av[4] = {a4.x, a4.y, a4.z, a4.w};
            float bv[4] = {b4.x, b4.y, b4.z, b4.w};
            #pragma unroll
            for (int i = 0; i < 4; i++)
                #pragma unroll
                for (int j = 0; j < 4; j++)
                    acc[i][j] = fmaf(av[i], bv[j], acc[i][j]);
        }
        __syncthreads();
    }
    float bn[4];
    #pragma unroll
    for (int j = 0; j < 4; j++) {
        float bb = 0.f;
        if (bias1) bb += bias1[n0 + tn * 4 + j];
        if (bias2) bb += bias2[n0 + tn * 4 + j];
        bn[j] = bb;
    }
    #pragma unroll
    for (int i = 0; i < 4; i++) {
        float4 o;
        o.x = acc[i][0] + bn[0]; o.y = acc[i][1] + bn[1];
        o.z = acc[i][2] + bn[2]; o.w = acc[i][3] + bn[3];
        *(float4*)(C + (size_t)(m0 + tm * 4 + i) * N + n0 + tn * 4) = o;
    }
}

// ---------------- LayerNorm + ReLU in place ----------------
__global__ __launch_bounds__(256)
void ln_relu_kernel(float* __restrict__ X, const float* __restrict__ g,
                    const float* __restrict__ bb)
{
    __shared__ float red[256];
    __shared__ float stat[2];
    const int row = blockIdx.x, t = threadIdx.x;
    float x0 = X[(size_t)row * 512 + t];
    float x1 = X[(size_t)row * 512 + 256 + t];
    red[t] = x0 + x1;
    __syncthreads();
    for (int o = 128; o > 0; o >>= 1) { if (t < o) red[t] += red[t + o]; __syncthreads(); }
    if (t == 0) stat[0] = red[0] * (1.f / 512.f);
    __syncthreads();
    float mu = stat[0];
    float d0 = x0 - mu, d1 = x1 - mu;
    red[t] = d0 * d0 + d1 * d1;
    __syncthreads();
    for (int o = 128; o > 0; o >>= 1) { if (t < o) red[t] += red[t + o]; __syncthreads(); }
    if (t == 0) stat[1] = red[0] * (1.f / 512.f);
    __syncthreads();
    float rs = rsqrtf(stat[1] + 1e-5f);
    float y0 = d0 * rs * g[t] + bb[t];
    float y1 = d1 * rs * g[256 + t] + bb[256 + t];
    X[(size_t)row * 512 + t] = fmaxf(y0, 0.f);
    X[(size_t)row * 512 + 256 + t] = fmaxf(y1, 0.f);
}

// ---------------- codebook row squared-norms ----------------
__global__ __launch_bounds__(256)
void rownorm_kernel(const float* __restrict__ Ein, float* __restrict__ norms)
{
    __shared__ float red[256];
    const int row = blockIdx.x, t = threadIdx.x;
    float a = Ein[(size_t)row * 512 + t];
    float b = Ein[(size_t)row * 512 + 256 + t];
    red[t] = a * a + b * b;
    __syncthreads();
    for (int o = 128; o > 0; o >>= 1) { if (t < o) red[t] += red[t + o]; __syncthreads(); }
    if (t == 0) norms[row] = red[0];
}

// ---------------- VQ argmin + STE update ----------------
__global__ __launch_bounds__(256)
void vq_update_kernel(const float* __restrict__ D, const float* __restrict__ norms,
                      const float* __restrict__ cb, float* __restrict__ residual,
                      float* __restrict__ quant, float* __restrict__ loss_acc,
                      int first)
{
    __shared__ unsigned long long red[256];
    __shared__ float fred[256];
    __shared__ int sidx;
    __shared__ float sdmin;
    const int tok = blockIdx.x, t = threadIdx.x;
    unsigned long long best = ~0ull;
    #pragma unroll
    for (int i = 0; i < 4; i++) {
        int k = t + i * 256;
        float d = fmaf(-2.f, D[(size_t)tok * 1024 + k], norms[k]);
        unsigned u = __float_as_uint(d);
        u = (u & 0x80000000u) ? ~u : (u | 0x80000000u);
        unsigned long long p = ((unsigned long long)u << 32) | (unsigned)k;
        best = p < best ? p : best;
    }
    red[t] = best;
    __syncthreads();
    for (int o = 128; o > 0; o >>= 1) {
        if (t < o) red[t] = red[t + o] < red[t] ? red[t + o] : red[t];
        __syncthreads();
    }
    if (t == 0) {
        unsigned long long r0 = red[0];
        sidx = (int)(r0 & 0xffffffffu);
        unsigned uv = (unsigned)(r0 >> 32);
        unsigned orig = (uv & 0x80000000u) ? (uv ^ 0x80000000u) : ~uv;
        sdmin = __uint_as_float(orig);
    }
    float r0v = residual[(size_t)tok * 512 + t];
    float r1v = residual[(size_t)tok * 512 + 256 + t];
    fred[t] = r0v * r0v + r1v * r1v;
    __syncthreads();
    for (int o = 128; o > 0; o >>= 1) { if (t < o) fred[t] += fred[t + o]; __syncthreads(); }
    int idx = sidx;
    if (t == 0) atomicAdd(loss_acc, sdmin + fred[0]);
    const float* E = cb + (size_t)idx * 512;
    float e0 = E[t], e1 = E[256 + t];
    float q0 = r0v + (e0 - r0v);
    float q1 = r1v + (e1 - r1v);
    residual[(size_t)tok * 512 + t]       = r0v - q0;
    residual[(size_t)tok * 512 + 256 + t] = r1v - q1;
    if (first) {
        quant[(size_t)tok * 512 + t]       = q0;
        quant[(size_t)tok * 512 + 256 + t] = q1;
    } else {
        quant[(size_t)tok * 512 + t]       += q0;
        quant[(size_t)tok * 512 + 256 + t] += q1;
    }
}

// ---------------- fused 2-layer LSTM: fence-free coherent exchange ----------------
#define GRPSZ 32
#define NGRP 8

__device__ __forceinline__ void wait_vm0() {
    asm volatile("s_waitcnt vmcnt(0)" ::: "memory");
}

// 4 coherent 16B loads (bypass stale L1/L2), one shared drain.
__device__ __forceinline__ void ld4_cg(float4& a, float4& b, float4& c, float4& d,
                                       const float4* p0, const float4* p1,
                                       const float4* p2, const float4* p3)
{
    asm volatile(
        "global_load_dwordx4 %0, %4, off sc0 sc1\n\t"
        "global_load_dwordx4 %1, %5, off sc0 sc1\n\t"
        "global_load_dwordx4 %2, %6, off sc0 sc1\n\t"
        "global_load_dwordx4 %3, %7, off sc0 sc1\n\t"
        "s_waitcnt vmcnt(0)"
        : "=&v"(a), "=&v"(b), "=&v"(c), "=&v"(d)
        : "v"(p0), "v"(p1), "v"(p2), "v"(p3)
        : "memory");
}

// coherent-stage 32KB (8192 floats) global -> LDS, two rounds of 4x float4/thread
__device__ __forceinline__ void stage_cg(float* dst_lds, const float* src, int t)
{
    const float4* s4 = (const float4*)src;
    float4* d4 = (float4*)dst_lds;
    float4 a, b, c, d;
    ld4_cg(a, b, c, d, s4 + t, s4 + t + 256, s4 + t + 512, s4 + t + 768);
    d4[t] = a; d4[t + 256] = b; d4[t + 512] = c; d4[t + 768] = d;
    ld4_cg(a, b, c, d, s4 + t + 1024, s4 + t + 1280, s4 + t + 1536, s4 + t + 1792);
    d4[t + 1024] = a; d4[t + 1280] = b; d4[t + 1536] = c; d4[t + 1792] = d;
}

__device__ __forceinline__ void arrive_wait(unsigned* bar, int g, unsigned tgt)
{
    // monotonic hierarchical barrier; arrivals relaxed (caller drained vmem).
    // bounded spin -> terminates even if residency assumption breaks.
    unsigned r = __hip_atomic_fetch_add(bar + g * 32, 1u, __ATOMIC_RELAXED,
                                        __HIP_MEMORY_SCOPE_AGENT);
    if (r == tgt * GRPSZ - 1) {
        unsigned rr = __hip_atomic_fetch_add(bar + 256, 1u, __ATOMIC_RELAXED,
                                             __HIP_MEMORY_SCOPE_AGENT);
        if (rr == tgt * NGRP - 1)
            __hip_atomic_store(bar + 288, tgt, __ATOMIC_RELAXED,
                               __HIP_MEMORY_SCOPE_AGENT);
    }
    int spins = 0;
    while (__hip_atomic_load(bar + 288, __ATOMIC_RELAXED,
                             __HIP_MEMORY_SCOPE_AGENT) < tgt) {
        __builtin_amdgcn_s_sleep(4);
        if (++spins > 20000) break;
    }
}

__device__ __forceinline__ float dot32(const float* hb, const float (&w)[32])
{
    float a0 = 0.f, a1 = 0.f, a2 = 0.f, a3 = 0.f;
    #pragma unroll
    for (int k4 = 0; k4 < 8; k4++) {
        float4 h4 = ((const float4*)hb)[k4];
        a0 = fmaf(h4.x, w[k4 * 4 + 0], a0);
        a1 = fmaf(h4.y, w[k4 * 4 + 1], a1);
        a2 = fmaf(h4.z, w[k4 * 4 + 2], a2);
        a3 = fmaf(h4.w, w[k4 * 4 + 3], a3);
    }
    return (a0 + a1) + (a2 + a3);
}

// blocks 0..127: layer 1; blocks 128..255: layer 2 at step lag 1.
// All h exchange via sc0/sc1 write-through stores + sc0/sc1 loads: NO fences,
// L2 stays warm for P1/weights/H2out.
__global__ __launch_bounds__(256)
void lstm_fused_kernel(const float* __restrict__ P1,
                       const float* __restrict__ wh1,
                       const float* __restrict__ wi2,
                       const float* __restrict__ wh2,
                       const float* __restrict__ bi2,
                       const float* __restrict__ bh2,
                       float* __restrict__ H2out,
                       float* __restrict__ h1A, float* __restrict__ h1B,
                       float* __restrict__ h2A, float* __restrict__ h2B,
                       unsigned* __restrict__ bar)
{
    __shared__ float hl[16 * 512];     // 32 KB x-staging
    __shared__ float hl2[16 * 512];    // 32 KB h-staging (role 1)
    __shared__ float part[16 * 256];   // 16 KB partials
    __shared__ float gl[256];
    __shared__ float c_lds[64];

    const int t = threadIdx.x;
    const int role = blockIdx.x >> 7;
    const int bid = blockIdx.x & 127;
    const int cl = t & 15, ks = t >> 4;
    const int gate = cl >> 2, jj = cl & 3;
    const int j_base = bid * 4;
    const int cl_r = t >> 4, b_r = t & 15;
    const int gate_r = cl_r >> 2, jj_r = cl_r & 3;
    const int g = blockIdx.x >> 5;

    float wrh[32], wrx[32];
    {
        const float* whp = (role == 0) ? wh1 : wh2;
        const float* wrow = whp + (size_t)(gate * 512 + j_base + jj) * 512 + ks * 32;
        #pragma unroll
        for (int i = 0; i < 32; i++) wrh[i] = wrow[i];
    }
    if (role == 1) {
        const float* wrow = wi2 + (size_t)(gate * 512 + j_base + jj) * 512 + ks * 32;
        #pragma unroll
        for (int i = 0; i < 32; i++) wrx[i] = wrow[i];
    } else {
        #pragma unroll
        for (int i = 0; i < 32; i++) wrx[i] = 0.f;
    }
    float bias2v = 0.f;
    if (role == 1) {
        int col = gate_r * 512 + j_base + jj_r;
        bias2v = bi2[col] + bh2[col];
    }
    if (t < 64) {
        c_lds[t] = 0.f;
        float* h0 = (role == 0) ? h1A : h2A;
        __hip_atomic_store(&h0[(t >> 2) * 512 + j_base + (t & 3)], 0.f,
                           __ATOMIC_RELAXED, __HIP_MEMORY_SCOPE_AGENT);
    }
    wait_vm0();
    __syncthreads();
    if (t == 0) arrive_wait(bar, g, 1);
    __syncthreads();

    for (int s = 0; s < 513; s++) {
        if (role == 0) {
            if (s < 512) {
                const int step = s;
                const float* hin = (step & 1) ? h1B : h1A;
                float* hout = (step & 1) ? h1A : h1B;
                stage_cg(hl, hin, t);
                float pv = P1[(size_t)(b_r * 512 + step) * 2048 + gate_r * 512 + j_base + jj_r];
                __syncthreads();
                float accb[16];
                #pragma unroll
                for (int b = 0; b < 16; b++)
                    accb[b] = dot32(hl + b * 512 + ks * 32, wrh);
                #pragma unroll
                for (int b = 0; b < 16; b++)
                    part[ks * 256 + cl * 16 + b] = accb[b];
                __syncthreads();
                float gv = pv;
                #pragma unroll
                for (int k = 0; k < 16; k++)
                    gv += part[k * 256 + cl_r * 16 + b_r];
                gl[cl_r * 16 + b_r] = gv;
                __syncthreads();
                if (t < 64) {
                    int b = t >> 2, jr = t & 3;
                    float iv = gl[(0 + jr) * 16 + b];
                    float fv = gl[(4 + jr) * 16 + b];
                    float gg = gl[(8 + jr) * 16 + b];
                    float ov = gl[(12 + jr) * 16 + b];
                    float ig = 1.f / (1.f + expf(-iv));
                    float fg = 1.f / (1.f + expf(-fv));
                    float og = 1.f / (1.f + expf(-ov));
                    float cn = fg * c_lds[t] + ig * tanhf(gg);
                    float hn = og * tanhf(cn);
                    c_lds[t] = cn;
                    __hip_atomic_store(&hout[b * 512 + j_base + jr], hn,
                                       __ATOMIC_RELAXED, __HIP_MEMORY_SCOPE_AGENT);
                }
            }
        } else {
            if (s >= 1) {
                const int m = s - 1;
                const float* xin = (m & 1) ? h1A : h1B;   // h1[m]
                const float* hin = (m & 1) ? h2B : h2A;   // h2[m-1]
                float* hout = (m & 1) ? h2A : h2B;        // h2[m]
                stage_cg(hl, xin, t);
                stage_cg(hl2, hin, t);
                __syncthreads();
                float accb[16];
                #pragma unroll
                for (int b = 0; b < 16; b++)
                    accb[b] = dot32(hl + b * 512 + ks * 32, wrx)
                            + dot32(hl2 + b * 512 + ks * 32, wrh);
                #pragma unroll
                for (int b = 0; b < 16; b++)
                    part[ks * 256 + cl * 16 + b] = accb[b];
                __syncthreads();
                float gv = bias2v;
                #pragma unroll
                for (int k = 0; k < 16; k++)
                    gv += part[k * 256 + cl_r * 16 + b_r];
                gl[cl_r * 16 + b_r] = gv;
                __syncthreads();
                if (t < 64) {
                    int b = t >> 2, jr = t & 3;
                    float iv = gl[(0 + jr) * 16 + b];
                    float fv = gl[(4 + jr) * 16 + b];
                    float gg = gl[(8 + jr) * 16 + b];
                    float ov = gl[(12 + jr) * 16 + b];
                    float ig = 1.f / (1.f + expf(-iv));
                    float fg = 1.f / (1.f + expf(-fv));
                    float og = 1.f / (1.f + expf(-ov));
                    float cn = fg * c_lds[t] + ig * tanhf(gg);
                    float hn = og * tanhf(cn);
                    c_lds[t] = cn;
                    int j = j_base + jr;
                    __hip_atomic_store(&hout[b * 512 + j], hn,
                                       __ATOMIC_RELAXED, __HIP_MEMORY_SCOPE_AGENT);
                    H2out[(size_t)(b * 512 + m) * 512 + j] = hn;   // normal cached store
                }
            }
        }
        if (s < 512) {
            wait_vm0();                       // release: drain write-through h stores
            if (t == 0) arrive_wait(bar, g, (unsigned)(s + 2));
            __syncthreads();                  // waves 1-3 held here until flag seen
        }
    }
}

__global__ void finalize_loss_kernel(const float* __restrict__ acc, float* __restrict__ out)
{
    int q = threadIdx.x;
    if (q < 4) out[2621440 + q] = acc[q] * (1.f / 4194304.f);
}

extern "C" void kernel_launch(void* const* d_in, const int* in_sizes, int n_in,
                              void* d_out, int out_size, void* d_ws, size_t ws_size,
                              hipStream_t stream)
{
    const float* waveform  = (const float*)d_in[0];
    const float* enc_w     = (const float*)d_in[1];
    const float* enc_b     = (const float*)d_in[2];
    const float* ln_g      = (const float*)d_in[3];
    const float* ln_b      = (const float*)d_in[4];
    const float* codebooks = (const float*)d_in[5];
    const float* lstm_wi   = (const float*)d_in[6];
    const float* lstm_wh   = (const float*)d_in[7];
    const float* lstm_bi   = (const float*)d_in[8];
    const float* lstm_bh   = (const float*)d_in[9];
    const float* dec_w     = (const float*)d_in[10];
    const float* dec_b     = (const float*)d_in[11];
    float* out = (float*)d_out;

    float* ws = (float*)d_ws;                  // float offsets
    float* residual = ws;                      // 4,194,304
    float* quant    = ws + 4194304;            // 4,194,304
    float* H2       = ws + 8388608;            // 4,194,304
    float* big      = ws + 12582912;           // 16,777,216 (VQ D, then LSTM P1)
    float* h1A      = ws + 29360128;           // 8192
    float* h1B      = ws + 29368320;           // 8192
    float* h2A      = ws + 29376512;           // 8192
    float* h2B      = ws + 29384704;           // 8192
    float* norms    = ws + 29392896;           // 4096
    float* loss_acc = ws + 29396992;           // 16
    unsigned* bar   = (unsigned*)(ws + 29397504); // 512 u32

    hipMemsetAsync(loss_acc, 0, 16 * sizeof(float), stream);
    hipMemsetAsync(bar, 0, 512 * sizeof(unsigned), stream);

    // Encoder
    gemm64<false><<<dim3(8, 128), 256, 0, stream>>>(waveform, enc_w, residual,
                                                    8192, 512, 320, enc_b, nullptr);
    ln_relu_kernel<<<8192, 256, 0, stream>>>(residual, ln_g, ln_b);

    // Residual VQ
    rownorm_kernel<<<4096, 256, 0, stream>>>(codebooks, norms);
    for (int q = 0; q < 4; q++) {
        const float* cb = codebooks + (size_t)q * 1024 * 512;
        gemm64<true><<<dim3(16, 128), 256, 0, stream>>>(residual, cb, big,
                                                        8192, 1024, 512, nullptr, nullptr);
        vq_update_kernel<<<8192, 256, 0, stream>>>(big, norms + q * 1024, cb,
                                                   residual, quant, loss_acc + q, q == 0);
    }

    // P1 = quant @ wi1^T + bi1 + bh1
    gemm64<true><<<dim3(32, 128), 256, 0, stream>>>(quant, lstm_wi, big,
                                                    8192, 2048, 512, lstm_bi, lstm_bh);
    // Fused 2-layer LSTM — plain launch, fence-free coherent exchange
    lstm_fused_kernel<<<dim3(256), dim3(256), 0, stream>>>(
        big, lstm_wh, lstm_wi + (size_t)2048 * 512, lstm_wh + (size_t)2048 * 512,
        lstm_bi + 2048, lstm_bh + 2048, H2, h1A, h1B, h2A, h2B, bar);

    // Decoder -> d_out
    gemm64<false><<<dim3(5, 128), 256, 0, stream>>>(H2, dec_w, out,
                                                    8192, 320, 512, dec_b, nullptr);
    finalize_loss_kernel<<<1, 4, 0, stream>>>(loss_acc, out);
}